// Round 6
// baseline (225.034 us; speedup 1.0000x reference)
//
#include <hip/hip_runtime.h>
#include <hip/hip_bf16.h>

// Linear1d: out[B,256] = (x[B,512] @ W[256,512]^T) / 8 + 0.1*bias
// R10: LDS-pipe de-load via A-fragment reuse. Utilization counters imply
// SCLK ~1.1-1.3 GHz on this kernel (MfmaUtil and VALUBusy both read 2x low
// vs a 2.4GHz budget), at which clock the LDS pipe (~64K cyc/CU) IS the
// ~80us wall. Previous design: NT=1 B-tile/wave -> every ds_read_b128 feeds
// ONE MFMA. Now: 4-wave blocks, wave holds wf[16][2] (32 cols, 128 regs,
// launch_bounds(256,2) so no 128-reg spill), 1 A-read : 2 MFMA. ds_reads
// per work region halve (256->128); staging upgraded to ds_write_b128
// (thread converts 8 f32 -> one bf16x8 write). Everything else retained:
// bf16 staging, XOR swizzle both sides, counted-vmcnt lds_barrier, padded
// obuf coalesced epilogue, XCD-paired N-halves.

typedef __bf16 bf16;
typedef __attribute__((ext_vector_type(8))) __bf16 bf16x8;
typedef __attribute__((ext_vector_type(4))) __bf16 bf16x4;
typedef __attribute__((ext_vector_type(4))) float f32x4;

#define BATCH_ 65536
#define KDIM   512
#define NDIM   256
#define NHALF  128                 // N-cols per block
#define CHUNK_ROWS 16
#define CHUNKS 8                   // per block
#define ROWS_PER_BLOCK (CHUNK_ROWS * CHUNKS)   // 128
#define OPAD 132                   // obuf row stride in floats (bank stagger)

__global__ __launch_bounds__(256) void wcvt_kernel(const float* __restrict__ w,
                                                   bf16* __restrict__ wb) {
    int i = (blockIdx.x * 256 + threadIdx.x) * 4;
    f32x4 v = *(const f32x4*)(w + i);
    bf16x4 o;
    o[0] = (bf16)(v.x * 0.125f);
    o[1] = (bf16)(v.y * 0.125f);
    o[2] = (bf16)(v.z * 0.125f);
    o[3] = (bf16)(v.w * 0.125f);
    *(bf16x4*)(wb + i) = o;
}

// 256 threads x 128 B: thread t covers f32 elems [j*2048 + t*8 .. +8) per
// pass j (32 B contiguous -> 2 dwordx4), 4 passes = the 32 KB f32 chunk.
__device__ __forceinline__ void stage_issue(const float* xc, int tid, f32x4 (&r)[8]) {
#pragma unroll
    for (int j = 0; j < 4; ++j) {
        r[2 * j]     = *(const f32x4*)((const char*)xc + j * 8192 + tid * 32);
        r[2 * j + 1] = *(const f32x4*)((const char*)xc + j * 8192 + tid * 32 + 16);
    }
}

// Convert 8 f32 -> one bf16x8, ONE ds_write_b128 per pass.
// Pass j: row = j*4 + (t>>6) (wave-uniform), within-row byte off = (t&63)*16
// (consecutive lanes -> consecutive 16B: conflict-free), swizzled
// phys = row*1024 + (off ^ ((row&7)<<4)).
__device__ __forceinline__ void stage_write(bf16* buf, int tid, const f32x4 (&r)[8]) {
#pragma unroll
    for (int j = 0; j < 4; ++j) {
        const int row = j * 4 + (tid >> 6);
        const int off = (tid & 63) * 16;
        const int phys = row * 1024 + (off ^ ((row & 7) << 4));
        bf16x8 o;
        o[0] = (bf16)r[2 * j].x;     o[1] = (bf16)r[2 * j].y;
        o[2] = (bf16)r[2 * j].z;     o[3] = (bf16)r[2 * j].w;
        o[4] = (bf16)r[2 * j + 1].x; o[5] = (bf16)r[2 * j + 1].y;
        o[6] = (bf16)r[2 * j + 1].z; o[7] = (bf16)r[2 * j + 1].w;
        *(bf16x8*)((char*)buf + phys) = o;
    }
}

// 1 ds_read_b128 : 2 MFMA. Lane (q,l16) reads x[l16][kc*32+q*8 .. +8] at
// logical byte l16*1024 + kc*64 + q*16, physical ^= ((l16&7)<<4).
__device__ __forceinline__ void compute_chunk(const bf16* buf, const bf16x8 (&wf)[16][2],
                                              int l16, int q, f32x4 (&acc)[2]) {
    acc[0] = (f32x4)0.0f;
    acc[1] = (f32x4)0.0f;
    const char* base = (const char*)buf + l16 * 1024;
    const int xo = (l16 & 7) << 4;
#pragma unroll
    for (int kc = 0; kc < 16; ++kc) {
        bf16x8 a = *(const bf16x8*)(base + ((kc * 64 + q * 16) ^ xo));
        acc[0] = __builtin_amdgcn_mfma_f32_16x16x32_bf16(a, wf[kc][0], acc[0], 0, 0, 0);
        acc[1] = __builtin_amdgcn_mfma_f32_16x16x32_bf16(a, wf[kc][1], acc[1], 0, 0, 0);
    }
}

// Deposit acc into padded out-staging tile: row = q*4+rr, col = w*32+nt*16+l16.
// Per instr (fixed nt,rr): bank = (q*16 + l16 + c)%32 -> 2-way (free).
__device__ __forceinline__ void owrite(float* ob, int w, int l16, int q,
                                       const f32x4 (&acc)[2]) {
#pragma unroll
    for (int nt = 0; nt < 2; ++nt) {
        float* p = ob + (q * 4) * OPAD + w * 32 + nt * 16 + l16;
#pragma unroll
        for (int rr = 0; rr < 4; ++rr)
            p[rr * OPAD] = acc[nt][rr];
    }
}

// Coalesced store: 2 iters x (16B LDS read + dense dwordx4 store); a
// 32-thread row-group covers 512B dense (4 full 128B lines).
__device__ __forceinline__ void ostore(const float* ob, float* __restrict__ out,
                                       long row0, int half, int tid,
                                       const f32x4& bvv) {
    const int c4 = (tid & 31) * 4;
#pragma unroll
    for (int rr = 0; rr < 2; ++rr) {
        const int r2 = (tid >> 5) + rr * 8;
        f32x4 v = *(const f32x4*)(ob + r2 * OPAD + c4);
        v.x += bvv.x; v.y += bvv.y; v.z += bvv.z; v.w += bvv.w;
        *(f32x4*)(out + (row0 + r2) * NDIM + half * NHALF + c4) = v;
    }
}

// LDS-visibility barrier WITHOUT the vmcnt(0) drain __syncthreads would emit.
__device__ __forceinline__ void lds_barrier() {
    asm volatile("s_waitcnt lgkmcnt(0)" ::: "memory");
    __builtin_amdgcn_s_barrier();
    __builtin_amdgcn_sched_barrier(0);
}

__global__ __launch_bounds__(256, 2) void gemm_kernel(const float* __restrict__ x,
                                                      const bf16* __restrict__ wb,
                                                      const float* __restrict__ bias,
                                                      float* __restrict__ out) {
    __shared__ __align__(16) bf16 bufA[CHUNK_ROWS * KDIM];   // 16 KB
    __shared__ __align__(16) bf16 bufB[CHUNK_ROWS * KDIM];   // 16 KB
    __shared__ __align__(16) float obuf0[CHUNK_ROWS * OPAD]; // 8.25 KB
    __shared__ __align__(16) float obuf1[CHUNK_ROWS * OPAD]; // 8.25 KB

    const int tid  = threadIdx.x;
    const int lane = tid & 63;
    const int w    = tid >> 6;     // wave 0..3 -> 32 N-columns each
    const int q    = lane >> 4;
    const int l16  = lane & 15;

    // Pair N-halves on the SAME XCD: g and g+8 share rb, differ in half.
    const int g    = blockIdx.x;
    const int half = (g >> 3) & 1;
    const long rb  = (long)((g & 7) | ((g >> 4) << 3));
    const int n0   = half * NHALF + w * 32;
    const long row_base = rb * ROWS_PER_BLOCK;

    // Stationary W: wf[kc][nt] = W[n0+nt*16+l16][kc*32+q*8 .. +7] (128 regs)
    bf16x8 wf[16][2];
#pragma unroll
    for (int kc = 0; kc < 16; ++kc)
#pragma unroll
        for (int nt = 0; nt < 2; ++nt)
            wf[kc][nt] = *(const bf16x8*)(wb + (long)(n0 + nt * 16 + l16) * KDIM
                                             + kc * 32 + q * 8);

    // Per-thread bias fragment for the coalesced epilogue.
    f32x4 bvv;
    {
        f32x4 b = *(const f32x4*)(bias + half * NHALF + (tid & 31) * 4);
        bvv.x = 0.1f * b.x; bvv.y = 0.1f * b.y;
        bvv.z = 0.1f * b.z; bvv.w = 0.1f * b.w;
    }

    const float* xblk = x + row_base * KDIM;

    // Prologue: chunk 0 -> bufA.
    f32x4 r[8];
    stage_issue(xblk, tid, r);
    stage_write(bufA, tid, r);
    lds_barrier();

    f32x4 acc[2];
#pragma unroll 1
    for (int t = 0; t < CHUNKS; t += 2) {
        // ---- even chunk t: compute bufA -> obuf0; prefetch t+1 -> bufB ----
        if (t + 1 < CHUNKS)
            stage_issue(xblk + (long)(t + 1) * CHUNK_ROWS * KDIM, tid, r);
        compute_chunk(bufA, wf, l16, q, acc);
        owrite(obuf0, w, l16, q, acc);
        if (t + 1 < CHUNKS)
            stage_write(bufB, tid, r);
        lds_barrier();
        ostore(obuf0, out, row_base + (long)t * CHUNK_ROWS, half, tid, bvv);

        // ---- odd chunk t+1: compute bufB -> obuf1; prefetch t+2 -> bufA ----
        if (t + 2 < CHUNKS)
            stage_issue(xblk + (long)(t + 2) * CHUNK_ROWS * KDIM, tid, r);
        compute_chunk(bufB, wf, l16, q, acc);
        owrite(obuf1, w, l16, q, acc);
        if (t + 2 < CHUNKS)
            stage_write(bufA, tid, r);
        lds_barrier();
        ostore(obuf1, out, row_base + (long)(t + 1) * CHUNK_ROWS, half, tid, bvv);
    }
}

extern "C" void kernel_launch(void* const* d_in, const int* in_sizes, int n_in,
                              void* d_out, int out_size, void* d_ws, size_t ws_size,
                              hipStream_t stream) {
    const float* x    = (const float*)d_in[0];
    const float* w    = (const float*)d_in[1];
    const float* bias = (const float*)d_in[2];
    float* out = (float*)d_out;
    bf16* wb   = (bf16*)d_ws;   // 256*512*2 = 256 KB scratch

    wcvt_kernel<<<(NDIM * KDIM) / (256 * 4), 256, 0, stream>>>(w, wb);
    gemm_kernel<<<(BATCH_ / ROWS_PER_BLOCK) * 2, 256, 0, stream>>>(x, wb, bias, out);
}